// Round 9
// baseline (185.563 us; speedup 1.0000x reference)
//
#include <hip/hip_runtime.h>

namespace {

typedef float v2f __attribute__((ext_vector_type(2)));

constexpr int kW = 640;
constexpr unsigned kSpan = 230400u;   // 360*640
constexpr int kB1 = 900;              // k_stats blocks (256 pts each)
constexpr int kB2 = 1800;             // k_count blocks (128 pts each)
constexpr int kPPB2 = 128;
constexpr int kB3 = 900;              // k_zc blocks (256 pts each)
constexpr int kTail = 16;             // select tail blocks in k_count
constexpr unsigned kPoison = 0xAAAAAAAAu;

// ws offsets (bytes); ws is poisoned 0xAA before every run
constexpr size_t kOffMaxv   = 0;      // u64: f32 bits of maxv   (written by K1 tail)
constexpr size_t kOffL17    = 8;      // u64: double bits of loss17
constexpr size_t kOffSel    = 16;     // u32: selkey atomicMax target (init 0 by K1 tail)
constexpr size_t kOffC1     = 128;    // k_stats arrival counter (poison-based)
constexpr size_t kOffC2     = 192;    // k_count arrival counter
constexpr size_t kOffC3     = 256;    // k_zc arrival counter
constexpr size_t kOffPlanes = 512;    // 1024 * 16 = 16384
constexpr size_t kOffSP     = 17408;  // 900 * 48 = 43200 (ends 60608)
constexpr size_t kOffZP     = 60928;  // 900 * 32 = 28800 (ends 89728)
constexpr size_t kOffPart   = 98304;  // 1800 * 256 * 4 = 1,843,200 (ends 1,941,504)
constexpr size_t kOffPts    = 1966080; // 230400 * 16 = 3,686,400 (ends ~5.65 MB)

__device__ __forceinline__ void ast64(unsigned long long* p, unsigned long long v) {
  __hip_atomic_store(p, v, __ATOMIC_RELAXED, __HIP_MEMORY_SCOPE_AGENT);
}
__device__ __forceinline__ unsigned long long ald64(const unsigned long long* p) {
  return __hip_atomic_load(p, __ATOMIC_RELAXED, __HIP_MEMORY_SCOPE_AGENT);
}
__device__ __forceinline__ void ast32(unsigned* p, unsigned v) {
  __hip_atomic_store(p, v, __ATOMIC_RELAXED, __HIP_MEMORY_SCOPE_AGENT);
}
__device__ __forceinline__ unsigned ald32(const unsigned* p) {
  return __hip_atomic_load(p, __ATOMIC_RELAXED, __HIP_MEMORY_SCOPE_AGENT);
}

__device__ __forceinline__ unsigned rotl32(unsigned v, int r) {
  return (v << r) | (v >> (32 - r));
}

// Threefry-2x32, 20 rounds, key = (0, 42)  [jax.random.key(42)]
__device__ __forceinline__ void threefry(unsigned c0, unsigned c1,
                                         unsigned& o0, unsigned& o1) {
  const unsigned ks0 = 0u, ks1 = 42u, ks2 = 0x1BD11BDAu ^ 0u ^ 42u;
  unsigned x0 = c0 + ks0, x1 = c1 + ks1;
#define TFR(r) { x0 += x1; x1 = rotl32(x1, (r)); x1 ^= x0; }
  TFR(13) TFR(15) TFR(26) TFR(6)
  x0 += ks1; x1 += ks2 + 1u;
  TFR(17) TFR(29) TFR(16) TFR(24)
  x0 += ks2; x1 += ks0 + 2u;
  TFR(13) TFR(15) TFR(26) TFR(6)
  x0 += ks0; x1 += ks1 + 3u;
  TFR(17) TFR(29) TFR(16) TFR(24)
  x0 += ks1; x1 += ks2 + 4u;
  TFR(13) TFR(15) TFR(26) TFR(6)
  x0 += ks2; x1 += ks0 + 5u;
#undef TFR
  o0 = x0; o1 = x1;
}

__device__ __forceinline__ void pix_coords(float d, int row, int col, bool& valid,
                                           float& x, float& y, float& z) {
  valid = (d > 0.0f) && (d < 65535.0f);
  float z0 = d / 1000.0f;
  float x0 = z0 * ((float)col - 334.081f) / 460.585f;
  float y0 = z0 * ((float)row - 169.808f) / 460.268f;
  x = x0 * 1000.0f;
  y = y0 * 1000.0f;
  z = z0 * 1000.0f;
  if (x == 0.0f) x = 1e-7f;
  if (y == 0.0f) y = 1e-7f;
  if (z == 0.0f) z = 1e-7f;
}

// normalized point — identical expression wherever used (bitwise mask consistency)
__device__ __forceinline__ void make_pt(float d, int row, int col, float maxv,
                                        float& x, float& y, float& z) {
  bool v; float a, b, c;
  pix_coords(d, row, col, v, a, b, c);
  x = (v ? a : 0.f) / maxv;
  y = (v ? b : 0.f) / maxv;
  z = (v ? c : 0.f) / maxv;
}

__device__ __forceinline__ float get_thresh(int ep) {
  return (float)fmax(0.025 - 0.001 * (double)ep, 0.005);
}

// ========= K1: stats partials + raw pts; last block reduces, scalars, planes =========
__global__ __launch_bounds__(256) void k_stats(const float* __restrict__ fake,
                                               const float* __restrict__ real,
                                               float* __restrict__ out,
                                               char* __restrict__ ws) {
  unsigned long long* wMaxv = (unsigned long long*)(ws + kOffMaxv);
  unsigned long long* wL17 = (unsigned long long*)(ws + kOffL17);
  unsigned* wSel = (unsigned*)(ws + kOffSel);
  unsigned* ctr = (unsigned*)(ws + kOffC1);
  float4* planes = (float4*)(ws + kOffPlanes);
  unsigned long long* sp = (unsigned long long*)(ws + kOffSP);
  float4* ptsraw = (float4*)(ws + kOffPts);

  const int b = blockIdx.x, t = threadIdx.x;
  const int lane = t & 63, wid = t >> 6;

  __shared__ double sD0[4], sD1[4], sD2[4], sD3[4];
  __shared__ int sI0[4];
  __shared__ float sF0[4];
  __shared__ unsigned sArr;
  __shared__ float sMaxv;

  {
    int i = b * 256 + t;
    int row = i / kW, col = i - row * kW;
    bool vr, vf; float rx, ry, rz, fx, fy, fz;
    pix_coords(real[i], row, col, vr, rx, ry, rz);
    pix_coords(fake[i], row, col, vf, fx, fy, fz);
    // raw (unnormalized, mask-applied) point — later kernels divide by maxv
    ptsraw[i] = make_float4(vf ? fx : 0.f, vf ? fy : 0.f, vf ? fz : 0.f, 0.f);
    double dx2 = 0, dy2 = 0, dz2 = 0, dl2 = 0; int cc = 0;
    if (vr && vf) {
      float ddx = rx - fx, ddy = ry - fy, ddz = rz - fz;
      dx2 = (double)ddx * (double)ddx;
      dy2 = (double)ddy * (double)ddy;
      dz2 = (double)ddz * (double)ddz;
      double dl = log(fabs((double)rz)) - log(fabs((double)fz));
      dl2 = dl * dl;
      cc = 1;
    }
    float mx = vf ? fmaxf(fmaxf(fx, fy), fz) : 0.0f;
    for (int o = 32; o; o >>= 1) {
      dx2 += __shfl_down(dx2, o); dy2 += __shfl_down(dy2, o);
      dz2 += __shfl_down(dz2, o); dl2 += __shfl_down(dl2, o);
      cc += __shfl_down(cc, o);
      mx = fmaxf(mx, __shfl_down(mx, o));
    }
    if (lane == 0) { sD0[wid]=dx2; sD1[wid]=dy2; sD2[wid]=dz2; sD3[wid]=dl2;
                     sI0[wid]=cc; sF0[wid]=mx; }
    __syncthreads();
    if (t == 0) {
      unsigned long long* e = sp + (size_t)b * 6;
      ast64(e + 0, __double_as_longlong(sD0[0]+sD0[1]+sD0[2]+sD0[3]));
      ast64(e + 1, __double_as_longlong(sD1[0]+sD1[1]+sD1[2]+sD1[3]));
      ast64(e + 2, __double_as_longlong(sD2[0]+sD2[1]+sD2[2]+sD2[3]));
      ast64(e + 3, __double_as_longlong(sD3[0]+sD3[1]+sD3[2]+sD3[3]));
      ast64(e + 4, (unsigned long long)(sI0[0]+sI0[1]+sI0[2]+sI0[3]));
      float bm = fmaxf(fmaxf(sF0[0], sF0[1]), fmaxf(sF0[2], sF0[3]));
      ast64(e + 5, (unsigned long long)__float_as_uint(bm));
    }
  }
  __syncthreads();
  if (t == 0)
    sArr = __hip_atomic_fetch_add(ctr, 1u, __ATOMIC_ACQ_REL, __HIP_MEMORY_SCOPE_AGENT);
  __syncthreads();
  if (sArr != kPoison + (unsigned)(kB1 - 1)) return;   // only last arrival continues

  // ---- tail: global reduce + scalar losses + plane build ----
  {
    double gx = 0, gy = 0, gz = 0, gl = 0; int gc = 0; float gm = 0.f;
    for (int r = t; r < kB1; r += 256) {
      const unsigned long long* e = sp + (size_t)r * 6;
      gx += __longlong_as_double(ald64(e + 0));
      gy += __longlong_as_double(ald64(e + 1));
      gz += __longlong_as_double(ald64(e + 2));
      gl += __longlong_as_double(ald64(e + 3));
      gc += (int)ald64(e + 4);
      gm = fmaxf(gm, __uint_as_float((unsigned)ald64(e + 5)));
    }
    for (int o = 32; o; o >>= 1) {
      gx += __shfl_down(gx, o); gy += __shfl_down(gy, o);
      gz += __shfl_down(gz, o); gl += __shfl_down(gl, o);
      gc += __shfl_down(gc, o);
      gm = fmaxf(gm, __shfl_down(gm, o));
    }
    if (lane == 0) { sD0[wid]=gx; sD1[wid]=gy; sD2[wid]=gz; sD3[wid]=gl;
                     sI0[wid]=gc; sF0[wid]=gm; }
    __syncthreads();
    if (t == 0) {
      double SX = sD0[0]+sD0[1]+sD0[2]+sD0[3];
      double SY = sD1[0]+sD1[1]+sD1[2]+sD1[3];
      double SZ = sD2[0]+sD2[1]+sD2[2]+sD2[3];
      double SL = sD3[0]+sD3[1]+sD3[2]+sD3[3];
      int CN = sI0[0]+sI0[1]+sI0[2]+sI0[3];
      float MX = fmaxf(fmaxf(sF0[0], sF0[1]), fmaxf(sF0[2], sF0[3]));
      double cntd = (CN > 0) ? (double)CN : 1.0;
      double lossX = sqrt(SX / cntd);
      double lossY = sqrt(SY / cntd);
      double lossZ = sqrt(SZ / cntd);
      double rmse_log = 10000.0 * sqrt(SL / cntd);
      double loss17 = rmse_log * fabs(10.0 * (3.0 - exp(lossX) - exp(lossY) - exp(lossZ)));
      out[0] = (float)rmse_log;
      out[1] = (float)lossX;
      out[2] = (float)lossY;
      out[3] = (float)lossZ;
      out[5] = (float)loss17;
      ast64(wMaxv, (unsigned long long)__float_as_uint(MX));
      ast64(wL17, __double_as_longlong(loss17));
      ast32(wSel, 0u);                       // init atomicMax target (overwrite poison)
      sMaxv = MX;
    }
    __syncthreads();
  }
  {
    float maxv = sMaxv;
#pragma unroll
    for (int j = 0; j < 4; j++) {
      int pid = t * 4 + j;                   // 0..1023
      float4 pl;
      if (pid < 1000) {
        float px[3], py[3], pz[3];
#pragma unroll
        for (int v = 0; v < 3; v++) {
          unsigned p = 3u * (unsigned)pid + (unsigned)v;
          unsigned o0, o1;
          threefry(p, p + 3000u, o0, o1);    // JAX randint: multiplier wraps to 0 => o1 % span
          unsigned idx = o1 % kSpan;
          int row = (int)(idx / kW), col = (int)idx - row * kW;
          make_pt(fake[idx], row, col, maxv, px[v], py[v], pz[v]);
        }
        float ax = px[1]-px[0], ay = py[1]-py[0], az = pz[1]-pz[0];
        float bx = px[2]-px[0], by = py[2]-py[0], bz = pz[2]-pz[0];
        float nx = ay*bz - az*by;
        float ny = az*bx - ax*bz;
        float nz = ax*by - ay*bx;
        float nn = sqrtf(nx*nx + ny*ny + nz*nz);
        nx /= nn; ny /= nn; nz /= nn;
        float kk = -(nx*px[1] + ny*py[1] + nz*pz[1]);
        pl = make_float4(nx, ny, nz, kk);
      } else {
        pl = make_float4(0.f, 0.f, 0.f, 3e38f);   // dummy: never an inlier
      }
      planes[pid] = pl;   // plain store; consumed by next kernel (stream order)
    }
  }
}

// ========= K2: count from ptsraw (R5-proven shape, 1800 blocks); last-16 select =========
__global__ __launch_bounds__(256) void k_count(const int* __restrict__ epoch,
                                               char* __restrict__ ws) {
  const unsigned long long* wMaxv = (const unsigned long long*)(ws + kOffMaxv);
  unsigned* wSel = (unsigned*)(ws + kOffSel);
  unsigned* wC2 = (unsigned*)(ws + kOffC2);
  const float4* planes = (const float4*)(ws + kOffPlanes);
  unsigned* part = (unsigned*)(ws + kOffPart);
  const float4* ptsraw = (const float4*)(ws + kOffPts);

  const int b = blockIdx.x, t = threadIdx.x;
  const float th = get_thresh(*epoch);
  const float maxv = __uint_as_float((unsigned)*wMaxv);

  __shared__ float4 sPts[kPPB2];
  __shared__ uint4 sAcc[16][16];
  __shared__ unsigned sArr;

  // ---- stage my 128 normalized points (simple float4 load, R5 style) ----
  if (t < kPPB2) {
    float4 r = ptsraw[b * kPPB2 + t];
    sPts[t] = make_float4(r.x / maxv, r.y / maxv, r.z / maxv, 0.f);
  }
  // each lane owns 4 planes in registers
  float4 p0 = planes[t * 4 + 0], p1 = planes[t * 4 + 1];
  float4 p2 = planes[t * 4 + 2], p3 = planes[t * 4 + 3];
  v2f Ax = {p0.x, p1.x}, Ay = {p0.y, p1.y}, Az = {p0.z, p1.z}, Aw = {p0.w, p1.w};
  v2f Bx = {p2.x, p3.x}, By = {p2.y, p3.y}, Bz = {p2.z, p3.z}, Bw = {p2.w, p3.w};
  __syncthreads();

  unsigned c0 = 0, c1 = 0, c2 = 0, c3 = 0;
#pragma unroll 8
  for (int s = 0; s < kPPB2; ++s) {
    float4 q = sPts[s];                    // broadcast ds_read_b128
    v2f qx = {q.x, q.x}, qy = {q.y, q.y}, qz = {q.z, q.z};
    // per-half chain == fmaf(qx,a,fmaf(qy,b,fmaf(qz,c,d))) — matches k_zc scalar chain
    v2f dA = __builtin_elementwise_fma(qx, Ax,
             __builtin_elementwise_fma(qy, Ay,
             __builtin_elementwise_fma(qz, Az, Aw)));
    v2f dB = __builtin_elementwise_fma(qx, Bx,
             __builtin_elementwise_fma(qy, By,
             __builtin_elementwise_fma(qz, Bz, Bw)));
    c0 += (fabsf(dA.x) <= th) ? 1u : 0u;
    c1 += (fabsf(dA.y) <= th) ? 1u : 0u;
    c2 += (fabsf(dB.x) <= th) ? 1u : 0u;
    c3 += (fabsf(dB.y) <= th) ? 1u : 0u;
  }
  // counts <= 128 fit u8; one packed u32 store per thread (R5 style)
  ast32(&part[b * 256 + t],
        c0 | (c1 << 8) | (c2 << 16) | (c3 << 24));

  __syncthreads();   // drains vmcnt: packed count stores globally performed
  if (t == 0)
    sArr = __hip_atomic_fetch_add(wC2, 1u, __ATOMIC_ACQ_REL, __HIP_MEMORY_SCOPE_AGENT);
  __syncthreads();
  unsigned ret = sArr;
  if (ret < kPoison + (unsigned)(kB2 - kTail)) return;   // 1784 blocks exit here
  const int r = (int)(ret - (kPoison + (unsigned)(kB2 - kTail)));  // 0..15

  // ---- distributed select among the last-16 (co-arrived) blocks ----
  if (t == 0) {
    while (ald32(wC2) != kPoison + (unsigned)kB2) __builtin_amdgcn_s_sleep(2);
  }
  __syncthreads();
  {
    int owner = r * 16 + (t & 15);        // owner column 0..255
    int chunk = t >> 4;                   // 16 chunks x 113 rows (last: 105)
    int row0 = chunk * 113;
    int row1 = row0 + 113 < kB2 ? row0 + 113 : kB2;
    unsigned s0 = 0, s1 = 0, s2 = 0, s3 = 0;
    for (int row = row0; row < row1; ++row) {
      unsigned v = ald32(&part[row * 256 + owner]);
      s0 += v & 0xFFu;
      s1 += (v >> 8) & 0xFFu;
      s2 += (v >> 16) & 0xFFu;
      s3 += (v >> 24) & 0xFFu;
    }
    sAcc[t & 15][chunk] = make_uint4(s0, s1, s2, s3);
  }
  __syncthreads();
  {
    unsigned mykey = 0u;
    if (t < 16) {
      unsigned t0 = 0, t1 = 0, t2 = 0, t3 = 0;
      for (int j = 0; j < 16; ++j) {
        uint4 v = sAcc[t][j];
        t0 += v.x; t1 += v.y; t2 += v.z; t3 += v.w;
      }
      unsigned tot[4] = {t0, t1, t2, t3};
      int pbase = (r * 16 + t) * 4;
#pragma unroll
      for (int k = 0; k < 4; ++k) {
        int p = pbase + k;
        int score = ((int)tot[k] > 5000) ? (int)tot[k] : -1;   // MIN_POINTS, strict >
        unsigned key = ((unsigned)(score + 2) << 10) | (unsigned)(1023 - p);
        mykey = key > mykey ? key : mykey;
      }
    }
    for (int o = 32; o; o >>= 1) {
      unsigned other = __shfl_down(mykey, o);
      mykey = other > mykey ? other : mykey;
    }
    if (t == 0) atomicMax(wSel, mykey);   // visible to k_zc at kernel boundary
  }
}

// ========= K3: wide zc from ptsraw; last block finalizes =========
__global__ __launch_bounds__(256) void k_zc(const int* __restrict__ epoch,
                                            float* __restrict__ out,
                                            char* __restrict__ ws) {
  const unsigned long long* wMaxv = (const unsigned long long*)(ws + kOffMaxv);
  const unsigned long long* wL17 = (const unsigned long long*)(ws + kOffL17);
  const unsigned* wSel = (const unsigned*)(ws + kOffSel);
  unsigned* ctr = (unsigned*)(ws + kOffC3);
  const float4* planes = (const float4*)(ws + kOffPlanes);
  unsigned long long* zp = (unsigned long long*)(ws + kOffZP);
  const float4* ptsraw = (const float4*)(ws + kOffPts);

  const int b = blockIdx.x, t = threadIdx.x;
  const int lane = t & 63, wid = t >> 6;
  const float th = get_thresh(*epoch);
  const float maxv = __uint_as_float((unsigned)*wMaxv);

  __shared__ double sD0[4];
  __shared__ int sI0[4];
  __shared__ float sF0[4], sF1[4];
  __shared__ unsigned sArr;

  int best = 1023 - (int)(*wSel & 1023u);
  float4 pl = planes[best];
  const float a = pl.x, bb = pl.y, c = pl.z, d = pl.w;
  float n2 = a * a + bb * bb + c * c;
  float cos_t = c / sqrtf(n2);
  float sin_t = sqrtf((a * a + bb * bb) / n2);
  float sab = sqrtf(a * a + bb * bb);
  float u1 = bb / sab, u2 = -a / sab;
  const float r0 = -u2 * sin_t, r1 = u1 * sin_t, r2 = cos_t, tz = d / c;

  double sz = 0.0; int ic = 0; float zmx = -INFINITY, zmn = -INFINITY;  // zmn = max(-zc)
  {
    float4 rw = ptsraw[b * 256 + t];
    float qx = rw.x / maxv, qy = rw.y / maxv, qz = rw.z / maxv;   // == k_count staging
    // identical per-lane chain to k_count's pk_fma halves
    float dist = fmaf(qx, a, fmaf(qy, bb, fmaf(qz, c, d)));
    if (fabsf(dist) <= th) {
      float zc = fmaf(qx, r0, fmaf(qy, r1, (qz + tz) * r2));
      sz = (double)zc; ic = 1; zmx = zc; zmn = -zc;
    }
  }
  for (int o = 32; o; o >>= 1) {
    sz += __shfl_down(sz, o); ic += __shfl_down(ic, o);
    zmx = fmaxf(zmx, __shfl_down(zmx, o));
    zmn = fmaxf(zmn, __shfl_down(zmn, o));
  }
  if (lane == 0) { sD0[wid] = sz; sI0[wid] = ic; sF0[wid] = zmx; sF1[wid] = zmn; }
  __syncthreads();
  if (t == 0) {
    unsigned long long* e = zp + (size_t)b * 4;
    ast64(e + 0, __double_as_longlong(sD0[0]+sD0[1]+sD0[2]+sD0[3]));
    ast64(e + 1, (unsigned long long)(sI0[0]+sI0[1]+sI0[2]+sI0[3]));
    float bmx = fmaxf(fmaxf(sF0[0], sF0[1]), fmaxf(sF0[2], sF0[3]));
    float bmn = fmaxf(fmaxf(sF1[0], sF1[1]), fmaxf(sF1[2], sF1[3]));
    ast64(e + 2, (unsigned long long)__float_as_uint(bmx) |
                 ((unsigned long long)__float_as_uint(bmn) << 32));
  }
  __syncthreads();   // drains vmcnt
  if (t == 0)
    sArr = __hip_atomic_fetch_add(ctr, 1u, __ATOMIC_ACQ_REL, __HIP_MEMORY_SCOPE_AGENT);
  __syncthreads();
  if (sArr != kPoison + (unsigned)(kB3 - 1)) return;

  // ---- tail: final pmdg ----
  {
    double gs = 0.0; int gi = 0; float gmx = -INFINITY, gmn = -INFINITY;
    for (int r = t; r < kB3; r += 256) {
      const unsigned long long* e = zp + (size_t)r * 4;
      gs += __longlong_as_double(ald64(e + 0));
      gi += (int)ald64(e + 1);
      unsigned long long mm = ald64(e + 2);
      gmx = fmaxf(gmx, __uint_as_float((unsigned)(mm & 0xFFFFFFFFu)));
      gmn = fmaxf(gmn, __uint_as_float((unsigned)(mm >> 32)));
    }
    for (int o = 32; o; o >>= 1) {
      gs += __shfl_down(gs, o); gi += __shfl_down(gi, o);
      gmx = fmaxf(gmx, __shfl_down(gmx, o));
      gmn = fmaxf(gmn, __shfl_down(gmn, o));
    }
    if (lane == 0) { sD0[wid] = gs; sI0[wid] = gi; sF0[wid] = gmx; sF1[wid] = gmn; }
    __syncthreads();
    if (t == 0) {
      double S = sD0[0]+sD0[1]+sD0[2]+sD0[3];
      int IC = sI0[0]+sI0[1]+sI0[2]+sI0[3];
      float MX = fmaxf(fmaxf(sF0[0], sF0[1]), fmaxf(sF0[2], sF0[3]));
      float MN = fmaxf(fmaxf(sF1[0], sF1[1]), fmaxf(sF1[2], sF1[3]));
      double below = 0.0, above = 0.0;
      if (IC > 0) {
        double icd = (double)IC;
        double mean = S / icd;
        below = (double)MX - mean;    // sum(|zc - zmax|)/icnt  (all zc <= zmax)
        above = mean - (double)(-MN); // sum(|zc - zmin|)/icnt
      }
      if (above == 0.0) above = 1e-7;
      double pmdg = 1000.0 * (above + below);
      double loss17 = __longlong_as_double(*wL17);
      out[4] = (float)pmdg;
      out[6] = (float)(loss17 + pmdg);
    }
  }
}

}  // namespace

extern "C" void kernel_launch(void* const* d_in, const int* in_sizes, int n_in,
                              void* d_out, int out_size, void* d_ws, size_t ws_size,
                              hipStream_t stream) {
  (void)in_sizes; (void)n_in; (void)out_size; (void)ws_size;
  const float* fake = (const float*)d_in[0];
  const float* real = (const float*)d_in[1];
  const int* epoch = (const int*)d_in[2];
  float* out = (float*)d_out;
  char* ws = (char*)d_ws;

  k_stats<<<kB1, 256, 0, stream>>>(fake, real, out, ws);
  k_count<<<kB2, 256, 0, stream>>>(epoch, ws);
  k_zc<<<kB3, 256, 0, stream>>>(epoch, out, ws);
}

// Round 10
// 138.135 us; speedup vs baseline: 1.3433x; 1.3433x over previous
//
#include <hip/hip_runtime.h>

namespace {

typedef float v2f __attribute__((ext_vector_type(2)));

constexpr int kW = 640;
constexpr unsigned kSpan = 230400u;   // 360*640
constexpr int kB1 = 900;              // k_stats blocks (256 pts each)
constexpr int kB2 = 1024;             // k_count_zc blocks (225 pts each) — fast shape (R5)
constexpr int kPPB2 = 225;
constexpr int kTail = 64;             // tail blocks doing select+zc
constexpr int kSlice = 230400 / kTail; // 3600 pts per tail block
constexpr unsigned kPoison = 0xAAAAAAAAu;

// ws offsets (bytes); ws is poisoned 0xAA before every run
constexpr size_t kOffMaxv   = 0;      // u64: f32 bits of maxv   (written by K1 tail)
constexpr size_t kOffL17    = 8;      // u64: double bits of loss17
constexpr size_t kOffSel    = 16;     // u32: selkey atomicMax target (zeroed by K1 tail)
constexpr size_t kOffC1     = 128;    // k_stats arrival counter (poison-based)
constexpr size_t kOffC2     = 192;    // count arrival counter   (zeroed by K1 tail)
constexpr size_t kOffC2b    = 256;    // select-done counter     (zeroed by K1 tail)
constexpr size_t kOffC3     = 320;    // zc arrival counter      (zeroed by K1 tail)
constexpr size_t kOffPlanes = 512;    // 1024 * 16 = 16384
constexpr size_t kOffSP     = 17408;  // 900 * 48 = 43200 (ends 60608)
constexpr size_t kOffZP     = 60928;  // 64 * 32 = 2048
constexpr size_t kOffPart   = 65536;  // 1024 * 256 * 4 = 1,048,576

__device__ __forceinline__ void ast64(unsigned long long* p, unsigned long long v) {
  __hip_atomic_store(p, v, __ATOMIC_RELAXED, __HIP_MEMORY_SCOPE_AGENT);
}
__device__ __forceinline__ unsigned long long ald64(const unsigned long long* p) {
  return __hip_atomic_load(p, __ATOMIC_RELAXED, __HIP_MEMORY_SCOPE_AGENT);
}
__device__ __forceinline__ void ast32(unsigned* p, unsigned v) {
  __hip_atomic_store(p, v, __ATOMIC_RELAXED, __HIP_MEMORY_SCOPE_AGENT);
}
__device__ __forceinline__ unsigned ald32(const unsigned* p) {
  return __hip_atomic_load(p, __ATOMIC_RELAXED, __HIP_MEMORY_SCOPE_AGENT);
}

__device__ __forceinline__ unsigned rotl32(unsigned v, int r) {
  return (v << r) | (v >> (32 - r));
}

// Threefry-2x32, 20 rounds, key = (0, 42)  [jax.random.key(42)]
__device__ __forceinline__ void threefry(unsigned c0, unsigned c1,
                                         unsigned& o0, unsigned& o1) {
  const unsigned ks0 = 0u, ks1 = 42u, ks2 = 0x1BD11BDAu ^ 0u ^ 42u;
  unsigned x0 = c0 + ks0, x1 = c1 + ks1;
#define TFR(r) { x0 += x1; x1 = rotl32(x1, (r)); x1 ^= x0; }
  TFR(13) TFR(15) TFR(26) TFR(6)
  x0 += ks1; x1 += ks2 + 1u;
  TFR(17) TFR(29) TFR(16) TFR(24)
  x0 += ks2; x1 += ks0 + 2u;
  TFR(13) TFR(15) TFR(26) TFR(6)
  x0 += ks0; x1 += ks1 + 3u;
  TFR(17) TFR(29) TFR(16) TFR(24)
  x0 += ks1; x1 += ks2 + 4u;
  TFR(13) TFR(15) TFR(26) TFR(6)
  x0 += ks2; x1 += ks0 + 5u;
#undef TFR
  o0 = x0; o1 = x1;
}

__device__ __forceinline__ void pix_coords(float d, int row, int col, bool& valid,
                                           float& x, float& y, float& z) {
  valid = (d > 0.0f) && (d < 65535.0f);
  float z0 = d / 1000.0f;
  float x0 = z0 * ((float)col - 334.081f) / 460.585f;
  float y0 = z0 * ((float)row - 169.808f) / 460.268f;
  x = x0 * 1000.0f;
  y = y0 * 1000.0f;
  z = z0 * 1000.0f;
  if (x == 0.0f) x = 1e-7f;
  if (y == 0.0f) y = 1e-7f;
  if (z == 0.0f) z = 1e-7f;
}

// normalized point — identical expression wherever used (bitwise mask consistency)
__device__ __forceinline__ void make_pt(float d, int row, int col, float maxv,
                                        float& x, float& y, float& z) {
  bool v; float a, b, c;
  pix_coords(d, row, col, v, a, b, c);
  x = (v ? a : 0.f) / maxv;
  y = (v ? b : 0.f) / maxv;
  z = (v ? c : 0.f) / maxv;
}

__device__ __forceinline__ float get_thresh(int ep) {
  return (float)fmax(0.025 - 0.001 * (double)ep, 0.005);
}

// ========= K1: stats partials; last block reduces, scalars, planes, counter init =========
__global__ __launch_bounds__(256) void k_stats(const float* __restrict__ fake,
                                               const float* __restrict__ real,
                                               float* __restrict__ out,
                                               char* __restrict__ ws) {
  unsigned long long* wMaxv = (unsigned long long*)(ws + kOffMaxv);
  unsigned long long* wL17 = (unsigned long long*)(ws + kOffL17);
  unsigned* wSel = (unsigned*)(ws + kOffSel);
  unsigned* ctr = (unsigned*)(ws + kOffC1);
  unsigned* wC2 = (unsigned*)(ws + kOffC2);
  unsigned* wC2b = (unsigned*)(ws + kOffC2b);
  unsigned* wC3 = (unsigned*)(ws + kOffC3);
  float4* planes = (float4*)(ws + kOffPlanes);
  unsigned long long* sp = (unsigned long long*)(ws + kOffSP);

  const int b = blockIdx.x, t = threadIdx.x;
  const int lane = t & 63, wid = t >> 6;

  __shared__ double sD0[4], sD1[4], sD2[4], sD3[4];
  __shared__ int sI0[4];
  __shared__ float sF0[4];
  __shared__ unsigned sArr;
  __shared__ float sMaxv;

  {
    int i = b * 256 + t;
    int row = i / kW, col = i - row * kW;
    bool vr, vf; float rx, ry, rz, fx, fy, fz;
    pix_coords(real[i], row, col, vr, rx, ry, rz);
    pix_coords(fake[i], row, col, vf, fx, fy, fz);
    double dx2 = 0, dy2 = 0, dz2 = 0, dl2 = 0; int cc = 0;
    if (vr && vf) {
      float ddx = rx - fx, ddy = ry - fy, ddz = rz - fz;
      dx2 = (double)ddx * (double)ddx;
      dy2 = (double)ddy * (double)ddy;
      dz2 = (double)ddz * (double)ddz;
      double dl = log(fabs((double)rz)) - log(fabs((double)fz));
      dl2 = dl * dl;
      cc = 1;
    }
    float mx = vf ? fmaxf(fmaxf(fx, fy), fz) : 0.0f;
    for (int o = 32; o; o >>= 1) {
      dx2 += __shfl_down(dx2, o); dy2 += __shfl_down(dy2, o);
      dz2 += __shfl_down(dz2, o); dl2 += __shfl_down(dl2, o);
      cc += __shfl_down(cc, o);
      mx = fmaxf(mx, __shfl_down(mx, o));
    }
    if (lane == 0) { sD0[wid]=dx2; sD1[wid]=dy2; sD2[wid]=dz2; sD3[wid]=dl2;
                     sI0[wid]=cc; sF0[wid]=mx; }
    __syncthreads();
    if (t == 0) {
      unsigned long long* e = sp + (size_t)b * 6;
      ast64(e + 0, __double_as_longlong(sD0[0]+sD0[1]+sD0[2]+sD0[3]));
      ast64(e + 1, __double_as_longlong(sD1[0]+sD1[1]+sD1[2]+sD1[3]));
      ast64(e + 2, __double_as_longlong(sD2[0]+sD2[1]+sD2[2]+sD2[3]));
      ast64(e + 3, __double_as_longlong(sD3[0]+sD3[1]+sD3[2]+sD3[3]));
      ast64(e + 4, (unsigned long long)(sI0[0]+sI0[1]+sI0[2]+sI0[3]));
      float bm = fmaxf(fmaxf(sF0[0], sF0[1]), fmaxf(sF0[2], sF0[3]));
      ast64(e + 5, (unsigned long long)__float_as_uint(bm));
    }
  }
  __syncthreads();
  if (t == 0)
    sArr = __hip_atomic_fetch_add(ctr, 1u, __ATOMIC_ACQ_REL, __HIP_MEMORY_SCOPE_AGENT);
  __syncthreads();
  if (sArr != kPoison + (unsigned)(kB1 - 1)) return;   // only last arrival continues

  // ---- tail: global reduce + scalar losses + plane build + counter init ----
  {
    double gx = 0, gy = 0, gz = 0, gl = 0; int gc = 0; float gm = 0.f;
    for (int r = t; r < kB1; r += 256) {
      const unsigned long long* e = sp + (size_t)r * 6;
      gx += __longlong_as_double(ald64(e + 0));
      gy += __longlong_as_double(ald64(e + 1));
      gz += __longlong_as_double(ald64(e + 2));
      gl += __longlong_as_double(ald64(e + 3));
      gc += (int)ald64(e + 4);
      gm = fmaxf(gm, __uint_as_float((unsigned)ald64(e + 5)));
    }
    for (int o = 32; o; o >>= 1) {
      gx += __shfl_down(gx, o); gy += __shfl_down(gy, o);
      gz += __shfl_down(gz, o); gl += __shfl_down(gl, o);
      gc += __shfl_down(gc, o);
      gm = fmaxf(gm, __shfl_down(gm, o));
    }
    if (lane == 0) { sD0[wid]=gx; sD1[wid]=gy; sD2[wid]=gz; sD3[wid]=gl;
                     sI0[wid]=gc; sF0[wid]=gm; }
    __syncthreads();
    if (t == 0) {
      double SX = sD0[0]+sD0[1]+sD0[2]+sD0[3];
      double SY = sD1[0]+sD1[1]+sD1[2]+sD1[3];
      double SZ = sD2[0]+sD2[1]+sD2[2]+sD2[3];
      double SL = sD3[0]+sD3[1]+sD3[2]+sD3[3];
      int CN = sI0[0]+sI0[1]+sI0[2]+sI0[3];
      float MX = fmaxf(fmaxf(sF0[0], sF0[1]), fmaxf(sF0[2], sF0[3]));
      double cntd = (CN > 0) ? (double)CN : 1.0;
      double lossX = sqrt(SX / cntd);
      double lossY = sqrt(SY / cntd);
      double lossZ = sqrt(SZ / cntd);
      double rmse_log = 10000.0 * sqrt(SL / cntd);
      double loss17 = rmse_log * fabs(10.0 * (3.0 - exp(lossX) - exp(lossY) - exp(lossZ)));
      out[0] = (float)rmse_log;
      out[1] = (float)lossX;
      out[2] = (float)lossY;
      out[3] = (float)lossZ;
      out[5] = (float)loss17;
      ast64(wMaxv, (unsigned long long)__float_as_uint(MX));
      ast64(wL17, __double_as_longlong(loss17));
      ast32(wSel, 0u);     // overwrite poison: K2 atomicMax target
      ast32(wC2, 0u);      // K2 counters start at 0 (replay-deterministic)
      ast32(wC2b, 0u);
      ast32(wC3, 0u);
      sMaxv = MX;
    }
    __syncthreads();
  }
  {
    float maxv = sMaxv;
#pragma unroll
    for (int j = 0; j < 4; j++) {
      int pid = t * 4 + j;                   // 0..1023
      float4 pl;
      if (pid < 1000) {
        float px[3], py[3], pz[3];
#pragma unroll
        for (int v = 0; v < 3; v++) {
          unsigned p = 3u * (unsigned)pid + (unsigned)v;
          unsigned o0, o1;
          threefry(p, p + 3000u, o0, o1);    // JAX randint: multiplier wraps to 0 => o1 % span
          unsigned idx = o1 % kSpan;
          int row = (int)(idx / kW), col = (int)idx - row * kW;
          make_pt(fake[idx], row, col, maxv, px[v], py[v], pz[v]);
        }
        float ax = px[1]-px[0], ay = py[1]-py[0], az = pz[1]-pz[0];
        float bx = px[2]-px[0], by = py[2]-py[0], bz = pz[2]-pz[0];
        float nx = ay*bz - az*by;
        float ny = az*bx - ax*bz;
        float nz = ax*by - ay*bx;
        float nn = sqrtf(nx*nx + ny*ny + nz*nz);
        nx /= nn; ny /= nn; nz /= nn;
        float kk = -(nx*px[1] + ny*py[1] + nz*pz[1]);
        pl = make_float4(nx, ny, nz, kk);
      } else {
        pl = make_float4(0.f, 0.f, 0.f, 3e38f);   // dummy: never an inlier
      }
      planes[pid] = pl;   // plain store; consumed by next kernel (stream order)
    }
  }
}

// ===== K2: count (1024x225, fast shape) -> 64-block-parallel select + zc + final =====
__global__ __launch_bounds__(256) void k_count_zc(const float* __restrict__ fake,
                                                  const int* __restrict__ epoch,
                                                  float* __restrict__ out,
                                                  char* __restrict__ ws) {
  const unsigned long long* wMaxv = (const unsigned long long*)(ws + kOffMaxv);
  const unsigned long long* wL17 = (const unsigned long long*)(ws + kOffL17);
  unsigned* wSel = (unsigned*)(ws + kOffSel);
  unsigned* wC2 = (unsigned*)(ws + kOffC2);
  unsigned* wC2b = (unsigned*)(ws + kOffC2b);
  unsigned* wC3 = (unsigned*)(ws + kOffC3);
  const float4* planes = (const float4*)(ws + kOffPlanes);
  unsigned long long* zp = (unsigned long long*)(ws + kOffZP);
  unsigned* part = (unsigned*)(ws + kOffPart);

  const int b = blockIdx.x, t = threadIdx.x;
  const int lane = t & 63, wid = t >> 6;
  const float th = get_thresh(*epoch);
  const float maxv = __uint_as_float((unsigned)*wMaxv);

  __shared__ float4 sPts[kPPB2];
  __shared__ uint4 sAcc[4][64];
  __shared__ double sD0[4];
  __shared__ int sI0[4];
  __shared__ float sF0[4], sF1[4];
  __shared__ unsigned sArr;

  // ---- stage my 225 normalized points into LDS ----
  if (t < kPPB2) {
    int i = b * kPPB2 + t;
    int row = i / kW, col = i - row * kW;
    float x, y, z;
    make_pt(fake[i], row, col, maxv, x, y, z);
    sPts[t] = make_float4(x, y, z, 0.f);
  }
  // each lane owns 4 planes in registers
  float4 p0 = planes[t * 4 + 0], p1 = planes[t * 4 + 1];
  float4 p2 = planes[t * 4 + 2], p3 = planes[t * 4 + 3];
  v2f Ax = {p0.x, p1.x}, Ay = {p0.y, p1.y}, Az = {p0.z, p1.z}, Aw = {p0.w, p1.w};
  v2f Bx = {p2.x, p3.x}, By = {p2.y, p3.y}, Bz = {p2.z, p3.z}, Bw = {p2.w, p3.w};
  __syncthreads();

  unsigned c0 = 0, c1 = 0, c2 = 0, c3 = 0;
#pragma unroll 5
  for (int s = 0; s < kPPB2; ++s) {
    float4 q = sPts[s];                    // broadcast ds_read_b128
    v2f qx = {q.x, q.x}, qy = {q.y, q.y}, qz = {q.z, q.z};
    // per-half chain == fmaf(qx,a,fmaf(qy,b,fmaf(qz,c,d))) — matches zc scalar chain
    v2f dA = __builtin_elementwise_fma(qx, Ax,
             __builtin_elementwise_fma(qy, Ay,
             __builtin_elementwise_fma(qz, Az, Aw)));
    v2f dB = __builtin_elementwise_fma(qx, Bx,
             __builtin_elementwise_fma(qy, By,
             __builtin_elementwise_fma(qz, Bz, Bw)));
    c0 += (fabsf(dA.x) <= th) ? 1u : 0u;
    c1 += (fabsf(dA.y) <= th) ? 1u : 0u;
    c2 += (fabsf(dB.x) <= th) ? 1u : 0u;
    c3 += (fabsf(dB.y) <= th) ? 1u : 0u;
  }
  // counts <= 225 fit u8; one packed u32 store per thread
  ast32(&part[b * 256 + t], c0 | (c1 << 8) | (c2 << 16) | (c3 << 24));

  __syncthreads();   // drains vmcnt: packed count stores globally performed
  if (t == 0)
    sArr = __hip_atomic_fetch_add(wC2, 1u, __ATOMIC_ACQ_REL, __HIP_MEMORY_SCOPE_AGENT);
  __syncthreads();
  unsigned ret = sArr;
  if (ret < (unsigned)(kB2 - kTail)) return;   // 960 blocks exit here
  const int r = (int)(ret - (unsigned)(kB2 - kTail)) & (kTail - 1);  // 0..63

  // ---- wait for all counts (co-arrived blocks; short) ----
  if (t == 0) {
    while (ald32(wC2) != (unsigned)kB2) __builtin_amdgcn_s_sleep(2);
  }
  __syncthreads();

  // ---- distributed select: block r owns owner-cols [4r,4r+4) = planes [16r,16r+16) ----
  {
    int col = r * 4 + (t & 3);            // owner column
    int chunk = t >> 2;                   // 64 chunks x 16 rows = 1024 rows
    unsigned s0 = 0, s1 = 0, s2 = 0, s3 = 0;
    for (int row = chunk * 16; row < chunk * 16 + 16; ++row) {
      unsigned v = ald32(&part[row * 256 + col]);
      s0 += v & 0xFFu;
      s1 += (v >> 8) & 0xFFu;
      s2 += (v >> 16) & 0xFFu;
      s3 += (v >> 24) & 0xFFu;
    }
    sAcc[t & 3][chunk] = make_uint4(s0, s1, s2, s3);
  }
  __syncthreads();
  {
    unsigned mykey = 0u;
    if (t < 4) {
      unsigned t0 = 0, t1 = 0, t2 = 0, t3 = 0;
      for (int j = 0; j < 64; ++j) {
        uint4 v = sAcc[t][j];
        t0 += v.x; t1 += v.y; t2 += v.z; t3 += v.w;
      }
      unsigned tot[4] = {t0, t1, t2, t3};
      int pbase = (r * 4 + t) * 4;
#pragma unroll
      for (int k = 0; k < 4; ++k) {
        int p = pbase + k;
        int score = ((int)tot[k] > 5000) ? (int)tot[k] : -1;   // MIN_POINTS, strict >
        unsigned key = ((unsigned)(score + 2) << 10) | (unsigned)(1023 - p);
        mykey = key > mykey ? key : mykey;
      }
    }
    for (int o = 2; o; o >>= 1) {
      unsigned other = __shfl_down(mykey, o);
      mykey = other > mykey ? other : mykey;
    }
    if (t == 0) {
      atomicMax(wSel, mykey);
      __hip_atomic_fetch_add(wC2b, 1u, __ATOMIC_RELEASE, __HIP_MEMORY_SCOPE_AGENT);
      while (ald32(wC2b) != (unsigned)kTail) __builtin_amdgcn_s_sleep(2);
      sArr = __hip_atomic_load(wSel, __ATOMIC_ACQUIRE, __HIP_MEMORY_SCOPE_AGENT);
    }
  }
  __syncthreads();

  // ---- zc over my 1/64 slice (recomputed, bit-identical chain) ----
  {
    int best = 1023 - (int)(sArr & 1023u);
    float4 pl = planes[best];
    const float a = pl.x, bb = pl.y, c = pl.z, d = pl.w;
    float n2 = a * a + bb * bb + c * c;
    float cos_t = c / sqrtf(n2);
    float sin_t = sqrtf((a * a + bb * bb) / n2);
    float sab = sqrtf(a * a + bb * bb);
    float u1 = bb / sab, u2 = -a / sab;
    const float r0 = -u2 * sin_t, r1 = u1 * sin_t, r2 = cos_t, tz = d / c;

    double sz = 0.0; int ic = 0; float zmx = -INFINITY, zmn = -INFINITY; // zmn=max(-zc)
    for (int k = t; k < kSlice; k += 256) {
      int i = r * kSlice + k;
      int row = i / kW, col = i - row * kW;
      float qx, qy, qz;
      make_pt(fake[i], row, col, maxv, qx, qy, qz);
      // identical per-lane chain to the count pk_fma halves
      float dist = fmaf(qx, a, fmaf(qy, bb, fmaf(qz, c, d)));
      if (fabsf(dist) <= th) {
        float zc = fmaf(qx, r0, fmaf(qy, r1, (qz + tz) * r2));
        sz += (double)zc; ic++;
        zmx = fmaxf(zmx, zc);
        zmn = fmaxf(zmn, -zc);
      }
    }
    for (int o = 32; o; o >>= 1) {
      sz += __shfl_down(sz, o); ic += __shfl_down(ic, o);
      zmx = fmaxf(zmx, __shfl_down(zmx, o));
      zmn = fmaxf(zmn, __shfl_down(zmn, o));
    }
    if (lane == 0) { sD0[wid] = sz; sI0[wid] = ic; sF0[wid] = zmx; sF1[wid] = zmn; }
    __syncthreads();
    if (t == 0) {
      unsigned long long* e = zp + (size_t)r * 4;
      ast64(e + 0, __double_as_longlong(sD0[0]+sD0[1]+sD0[2]+sD0[3]));
      ast64(e + 1, (unsigned long long)(sI0[0]+sI0[1]+sI0[2]+sI0[3]));
      float bmx = fmaxf(fmaxf(sF0[0], sF0[1]), fmaxf(sF0[2], sF0[3]));
      float bmn = fmaxf(fmaxf(sF1[0], sF1[1]), fmaxf(sF1[2], sF1[3]));
      ast64(e + 2, (unsigned long long)__float_as_uint(bmx) |
                   ((unsigned long long)__float_as_uint(bmn) << 32));
    }
    __syncthreads();   // drains vmcnt
    if (t == 0)
      sArr = __hip_atomic_fetch_add(wC3, 1u, __ATOMIC_ACQ_REL, __HIP_MEMORY_SCOPE_AGENT);
    __syncthreads();
    if (sArr != (unsigned)(kTail - 1)) return;
  }

  // ---- final: reduce 64 zc partials in wave 0, pmdg, outputs ----
  if (t < 64) {
    double gs = 0.0; int gi = 0; float gmx = -INFINITY, gmn = -INFINITY;
    const unsigned long long* e = zp + (size_t)t * 4;
    gs = __longlong_as_double(ald64(e + 0));
    gi = (int)ald64(e + 1);
    unsigned long long mm = ald64(e + 2);
    gmx = __uint_as_float((unsigned)(mm & 0xFFFFFFFFu));
    gmn = __uint_as_float((unsigned)(mm >> 32));
    for (int o = 32; o; o >>= 1) {
      gs += __shfl_down(gs, o); gi += __shfl_down(gi, o);
      gmx = fmaxf(gmx, __shfl_down(gmx, o));
      gmn = fmaxf(gmn, __shfl_down(gmn, o));
    }
    if (t == 0) {
      double below = 0.0, above = 0.0;
      if (gi > 0) {
        double icd = (double)gi;
        double mean = gs / icd;
        below = (double)gmx - mean;    // sum(|zc - zmax|)/icnt  (all zc <= zmax)
        above = mean - (double)(-gmn); // sum(|zc - zmin|)/icnt
      }
      if (above == 0.0) above = 1e-7;
      double pmdg = 1000.0 * (above + below);
      double loss17 = __longlong_as_double(*wL17);
      out[4] = (float)pmdg;
      out[6] = (float)(loss17 + pmdg);
    }
  }
}

}  // namespace

extern "C" void kernel_launch(void* const* d_in, const int* in_sizes, int n_in,
                              void* d_out, int out_size, void* d_ws, size_t ws_size,
                              hipStream_t stream) {
  (void)in_sizes; (void)n_in; (void)out_size; (void)ws_size;
  const float* fake = (const float*)d_in[0];
  const float* real = (const float*)d_in[1];
  const int* epoch = (const int*)d_in[2];
  float* out = (float*)d_out;
  char* ws = (char*)d_ws;

  k_stats<<<kB1, 256, 0, stream>>>(fake, real, out, ws);
  k_count_zc<<<kB2, 256, 0, stream>>>(fake, epoch, out, ws);
}